// Round 4
// baseline (157.151 us; speedup 1.0000x reference)
//
#include <hip/hip_runtime.h>
#include <hip/hip_bf16.h>
#include <stdint.h>

#define B_   4
#define N_   10000
#define K_   16
#define D_   256
#define OUT_ 256
#define M_   (B_ * N_)          // 40000
#define TILES_ 625              // M / 64, exact
#define TPH    16384            // ushorts per (half,ks) B tile: 256 rows x 64 k

// y2c: bf16, 16 chunks of 16 cols; row = (n*4+b), 32 B/row, 1.28 MB/chunk
#define C16_ELEMS ((size_t)M_ * 16)     // 640,000 ushorts per chunk
// y1c: fp32,  32 chunks of  8 cols; row = (n*4+b), 32 B/row, 1.28 MB/chunk
#define C8_ELEMS  ((size_t)M_ * 8)      // 320,000 floats per chunk

typedef __attribute__((ext_vector_type(8))) short          short8;    // MFMA frag
typedef __attribute__((ext_vector_type(8))) unsigned short ushort8;
typedef __attribute__((ext_vector_type(4))) float          f32x4;
typedef __attribute__((ext_vector_type(4))) unsigned short ushort4_t;

__device__ inline unsigned short f2bf(float f) {
    __hip_bfloat16 h = __float2bfloat16(f);
    return *reinterpret_cast<unsigned short*>(&h);
}
__device__ inline float bf2f(unsigned short u) {
    unsigned int v = ((unsigned int)u) << 16;
    return __builtin_bit_cast(float, v);
}

// ---------------------------------------------------------------------------
// wprep: W (256 x 512 f32, row o = [W1_o | W2_o]) -> Wb bf16, tiled
// [half][ks][32KB] = PRE-SWIZZLED image of the LDS B-buffer gemm3 stages
// linearly via global_load_lds:
//   Bs[(row*128 + k*2) ^ ((row&7)<<4)] = W'[row][k]
// (XOR swizzle -> bank-conflict-free stride-128B b128 frag reads.)
// ---------------------------------------------------------------------------
__global__ __launch_bounds__(256) void wprep(const float* __restrict__ W,
                                             unsigned short* __restrict__ Wb) {
    const int g  = blockIdx.x * 256 + threadIdx.x;   // 0..32767
    const int h  = g >> 14;                          // half
    const int t  = g & 16383;
    const int ks = t >> 12;                          // k-slab 0..3
    const int rr = (t >> 4) & 255;                   // out-row 0..255
    const int kg = (t & 15) * 4;                     // k within slab, x4
    const float4 v = *(const float4*)(W + (size_t)rr * 512 + h * 256 + ks * 64 + kg);
    ushort4_t s;
    s.x = f2bf(v.x); s.y = f2bf(v.y); s.z = f2bf(v.z); s.w = f2bf(v.w);
    const int off = ((rr * 128 + kg * 2) ^ ((rr & 7) << 4)) >> 1;   // ushort idx
    *(ushort4_t*)(Wb + (size_t)(h * 4 + ks) * TPH + off) = s;
}

// ---------------------------------------------------------------------------
// gemm3: y[m, o'] = x[m, :] . W'[o', :]   (M=40000, K=256, N'=512)
// Round-3 proven K-loop (tile 64m x 256n, 8 waves, BK=64, swizzled LDS,
// reg-staged A with early next-phase loads). BOTH halves use swapped
// mfma(b,a) -> D[row=o, col=m]: lane holds 4 consecutive o-cols -> packed,
// fully-coalesced chunked stores:
//   half 0 -> y1c fp32 CW8  chunks (16-B f32x4 stores)   [self term, fp32 kept]
//   half 1 -> y2c bf16 CW16 chunks ( 8-B ushort4 stores) [gather operand]
// Halves of an m-tile share an XCD (x fetched from HBM once).
// ---------------------------------------------------------------------------
__global__ __launch_bounds__(512) void gemm3(const float* __restrict__ x,
                                             const unsigned short* __restrict__ Wb,
                                             float* __restrict__ y1c,
                                             unsigned short* __restrict__ y2c) {
    __shared__ unsigned short As[64 * 64];    //  8 KB
    __shared__ unsigned short Bs[256 * 64];   // 32 KB

    const int tid  = threadIdx.x;
    const int w    = tid >> 6;
    const int lane = tid & 63;
    const int q    = lane >> 4;
    const int r16  = lane & 15;
    const int wm   = w >> 2;          // 0..1 : 32-row strip
    const int wn   = w & 3;           // 0..3 : 64-col strip

    const int bi   = blockIdx.x;
    const int xcd  = bi & 7;
    const int u    = bi >> 3;
    const int g    = (u >> 1) * 8 + xcd;
    const int half = u & 1;
    if (g >= TILES_) return;
    const int tile_m = g * 64;

    // ---- A staging coords: 64 rows x 64 k fp32; 512 thr x 16 f32 ----
    const int arow = tid >> 3;              // 0..63
    const int akg  = (tid & 7) * 8;         // 0,8,...,56
    const float* ap = x + (size_t)(tile_m + arow) * D_ + akg;
    const unsigned int awoff = (unsigned)((arow * 128 + akg * 2) ^ ((arow & 7) << 4));

    // ---- B staging: linear copy of the pre-swizzled 32-KB tile ----
    const unsigned short* wsrc0 = Wb + (size_t)(half * 4) * TPH + tid * 8;

    const unsigned int sw = (unsigned)((r16 & 7) << 4);   // frag-read swizzle

    f32x4 acc[2][4] = {};

    // prologue: load+stage phase 0
    float4 c0 = *(const float4*)ap;
    float4 c1 = *(const float4*)(ap + 4);
#pragma unroll
    for (int i2 = 0; i2 < 4; ++i2) {
        __builtin_amdgcn_global_load_lds(
            (const __attribute__((address_space(1))) void*)(wsrc0 + i2 * 4096),
            (__attribute__((address_space(3))) void*)(Bs + tid * 8 + i2 * 4096),
            16, 0, 0);
    }
    {
        ushort8 s;
        s[0] = f2bf(c0.x); s[1] = f2bf(c0.y); s[2] = f2bf(c0.z); s[3] = f2bf(c0.w);
        s[4] = f2bf(c1.x); s[5] = f2bf(c1.y); s[6] = f2bf(c1.z); s[7] = f2bf(c1.w);
        *(ushort8*)((char*)As + awoff) = s;
    }
    __syncthreads();

#pragma unroll
    for (int ks = 0; ks < 4; ++ks) {
        float4 n0, n1;
        if (ks < 3) {                       // next-phase A loads, issued early
            n0 = *(const float4*)(ap + (ks + 1) * 64);
            n1 = *(const float4*)(ap + (ks + 1) * 64 + 4);
        }

#pragma unroll
        for (int ksub = 0; ksub < 2; ++ksub) {
            short8 a[2], bf[4];
#pragma unroll
            for (int i = 0; i < 2; ++i) {
                const unsigned int ad =
                    (unsigned)((wm * 32 + i * 16 + r16) * 128 + ksub * 64 + q * 16) ^ sw;
                a[i] = *(const short8*)((const char*)As + ad);
            }
#pragma unroll
            for (int j = 0; j < 4; ++j) {
                const unsigned int bd =
                    (unsigned)((wn * 64 + j * 16 + r16) * 128 + ksub * 64 + q * 16) ^ sw;
                bf[j] = *(const short8*)((const char*)Bs + bd);
            }
            // swapped operands for BOTH halves: D[row=o, col=m]
#pragma unroll
            for (int i = 0; i < 2; ++i)
#pragma unroll
                for (int j = 0; j < 4; ++j)
                    acc[i][j] = __builtin_amdgcn_mfma_f32_16x16x32_bf16(bf[j], a[i], acc[i][j], 0, 0, 0);
        }

        if (ks < 3) {
            __syncthreads();
            const unsigned short* wsrc = wsrc0 + (size_t)(ks + 1) * TPH;
#pragma unroll
            for (int i2 = 0; i2 < 4; ++i2) {
                __builtin_amdgcn_global_load_lds(
                    (const __attribute__((address_space(1))) void*)(wsrc + i2 * 4096),
                    (__attribute__((address_space(3))) void*)(Bs + tid * 8 + i2 * 4096),
                    16, 0, 0);
            }
            ushort8 s;
            s[0] = f2bf(n0.x); s[1] = f2bf(n0.y); s[2] = f2bf(n0.z); s[3] = f2bf(n0.w);
            s[4] = f2bf(n1.x); s[5] = f2bf(n1.y); s[6] = f2bf(n1.z); s[7] = f2bf(n1.w);
            *(ushort8*)((char*)As + awoff) = s;
            __syncthreads();
        }
    }

    // ---- epilogue: chunked stores (lane = 4 consecutive o-cols) ----
#pragma unroll
    for (int i = 0; i < 2; ++i) {
        const int m  = tile_m + wm * 32 + i * 16 + r16;
        const int bb = (m >= N_) + (m >= 2 * N_) + (m >= 3 * N_);
        const int n  = m - bb * N_;
        const size_t row = (size_t)(n * B_ + bb);
        if (half == 0) {
            // y1c fp32, CW8 chunks
#pragma unroll
            for (int j = 0; j < 4; ++j) {
                const int o2 = wn * 64 + j * 16 + q * 4;
                f32x4 p;
                p[0] = acc[i][j][0]; p[1] = acc[i][j][1];
                p[2] = acc[i][j][2]; p[3] = acc[i][j][3];
                *(f32x4*)(y1c + (size_t)(o2 >> 3) * C8_ELEMS + row * 8 + (o2 & 7)) = p;
            }
        } else {
            // y2c bf16, CW16 chunks
#pragma unroll
            for (int j = 0; j < 4; ++j) {
                const int o2 = wn * 64 + j * 16 + q * 4;
                ushort4_t p;
                p.x = f2bf(acc[i][j][0]); p.y = f2bf(acc[i][j][1]);
                p.z = f2bf(acc[i][j][2]); p.w = f2bf(acc[i][j][3]);
                *(ushort4_t*)(y2c + (size_t)(o2 >> 4) * C16_ELEMS + row * 16 + (o2 & 15)) = p;
            }
        }
    }
}

// ---------------------------------------------------------------------------
// gather_out: out[b,n,o] = relu( y1[b,n,o] + (1/cnt) sum_k y2[b,neigh[n,k],o]
//                                + bias[o] )
// Fully L2-local per XCD: chunk c (16 cols) -> XCD c&7; per-XCD working set =
// y2 chunk (1.28 MB) + y1 chunks 2c,2c+1 (2.56 MB) = 3.84 MB < 4 MB L2.
// Chunk-sets {0..7} then {8..15} run sequentially per XCD (block ordering).
// 128-thr blocks: 16 nodes x 4 b x 2 col-halves; 8 consecutive threads read
// one contiguous 128-B neighbor row group (fully coalesced 16-B gathers).
// Only the nt out-stores leave the XCD.
// ---------------------------------------------------------------------------
__global__ __launch_bounds__(128) void gather_out(const unsigned short* __restrict__ y2c,
                                                  const float* __restrict__ y1c,
                                                  const int*   __restrict__ neigh,
                                                  const float* __restrict__ bias,
                                                  float* __restrict__ out) {
    const int bi  = blockIdx.x;
    const int lo  = bi < 5000;
    const int c   = (bi & 7) + (lo ? 0 : 8);          // chunk 0..15, XCD = c&7
    const int g   = (lo ? bi : bi - 5000) >> 3;       // 0..624
    const int n0  = g * 16;
    const int tid = threadIdx.x;

    __shared__ int   idx_s[16 * K_];   // 256 ints
    __shared__ float inv_s[16];

    idx_s[tid]       = neigh[n0 * K_ + tid];
    idx_s[tid + 128] = neigh[n0 * K_ + tid + 128];
    __syncthreads();
    if (tid < 16) {
        int cnt = 0;
#pragma unroll
        for (int k = 0; k < K_; ++k) cnt += idx_s[tid * K_ + k] >= 0 ? 1 : 0;
        inv_s[tid] = 1.0f / (float)(cnt > 1 ? cnt : 1);
    }
    __syncthreads();

    const int h  = tid & 1;          // col half (8 cols)
    const int tl = tid >> 1;         // task 0..63
    const int ns = tl >> 2;          // node_sub 0..15
    const int b  = tl & 3;           // batch

    const unsigned short* ycc = y2c + (size_t)c * C16_ELEMS;

    int jj[K_];
#pragma unroll
    for (int k = 0; k < K_; ++k) jj[k] = idx_s[ns * K_ + k];

    // 16 independent 16-B gather loads from the L2-resident chunk
    ushort8 vv[K_];
#pragma unroll
    for (int k = 0; k < K_; ++k) {
        const int jc = jj[k] >= 0 ? jj[k] : 0;
        vv[k] = *(const ushort8*)(ycc + ((size_t)jc * B_ + b) * 16 + h * 8);
    }

    // self term from the L2-resident y1 chunk (2c + h) + bias
    const size_t row = (size_t)((n0 + ns) * B_ + b);
    const float* yrow = y1c + (size_t)(2 * c + h) * C8_ELEMS + row * 8;
    const f32x4 s0 = *(const f32x4*)(yrow);
    const f32x4 s1 = *(const f32x4*)(yrow + 4);
    const f32x4 b0 = *(const f32x4*)(bias + c * 16 + h * 8);
    const f32x4 b1 = *(const f32x4*)(bias + c * 16 + h * 8 + 4);

    float acc[8] = {0.f, 0.f, 0.f, 0.f, 0.f, 0.f, 0.f, 0.f};
#pragma unroll
    for (int k = 0; k < K_; ++k) {
        const float m = jj[k] >= 0 ? 1.f : 0.f;
#pragma unroll
        for (int e = 0; e < 8; ++e) acc[e] += bf2f(vv[k][e]) * m;
    }
    const float inv = inv_s[ns];

    f32x4 o0, o1;
#pragma unroll
    for (int e = 0; e < 4; ++e) {
        float v0 = acc[e] * inv + s0[e] + b0[e];
        float v1 = acc[e + 4] * inv + s1[e] + b1[e];
        o0[e] = v0 > 0.f ? v0 : 0.f;
        o1[e] = v1 > 0.f ? v1 : 0.f;
    }
    // out: (b, n0+ns) row, cols c*16 + h*8 .. +8  (never re-read -> nt)
    float* op = out + ((size_t)b * N_ + n0 + ns) * OUT_ + c * 16 + h * 8;
    __builtin_nontemporal_store(o0, (f32x4*)op);
    __builtin_nontemporal_store(o1, (f32x4*)(op + 4));
}

// ---------------------------------------------------------------------------
extern "C" void kernel_launch(void* const* d_in, const int* in_sizes, int n_in,
                              void* d_out, int out_size, void* d_ws, size_t ws_size,
                              hipStream_t stream) {
    const float* x     = (const float*)d_in[0];   // (4, 10000, 256) fp32
    const int*   neigh = (const int*)d_in[1];     // (10000, 16) int32
    const float* W     = (const float*)d_in[2];   // (256, 512) fp32
    const float* bias  = (const float*)d_in[3];   // (256,) fp32
    float*       out   = (float*)d_out;           // (4, 10000, 256) fp32

    unsigned short* Wb  = (unsigned short*)d_ws;              // 256 KB
    float*          y1c = (float*)(Wb + 8 * TPH);             // 32 x 1.28 MB = 41 MB
    unsigned short* y2c = (unsigned short*)(y1c + 32 * C8_ELEMS); // 16 x 1.28 MB
    
    wprep<<<128, 256, 0, stream>>>(W, Wb);
    gemm3<<<158 * 8, 512, 0, stream>>>(x, Wb, y1c, y2c);      // 1264 blocks
    gather_out<<<10000, 128, 0, stream>>>(y2c, y1c, neigh, bias, out);
}